// Round 13
// baseline (1122.047 us; speedup 1.0000x reference)
//
#include <hip/hip_runtime.h>
#include <hip/hip_fp16.h>

// ButterflyRotation R13: MEASUREMENT ROUND (component ablation on R10).
// R10 structure throughout: BLOCK=512, 2 rows/block packed v2f in 32 KiB
// interleaved LDS, radix-8 x 4 phases, f16 {1-cos,sin} transposed table,
// one-phase-ahead angle prefetch, lgkm-only barriers, grid 4096.
// Variants (each REP=2 passes, full grid, d_out overwritten; FULL runs LAST
// so final d_out is correct):
//   MODE 1 noROT: rot chains removed (keep-alive dd/ss)     -> VALU share
//   MODE 2 noANG: angle loads+unpack removed (const angles) -> angle share
//   MODE 3 noLDS: LDS round-trips + barriers removed        -> LDS share
//   MODE 0 full : R10-exact x2 (correct output)             -> baseline x2
// Read per-dispatch dur_us from rocprof rows, NOT the summed bench dur.

#define DIM    4096
#define LAYERS 12
#define BATCH  8192
#define NANG   2048
#define BLOCK  512
#define REP    2

typedef unsigned int u32;
typedef float v2f __attribute__((ext_vector_type(2)));

#define BAR() do {                                             \
    asm volatile("s_waitcnt lgkmcnt(0)" ::: "memory");         \
    __builtin_amdgcn_sched_barrier(0);                         \
    __builtin_amdgcn_s_barrier();                              \
} while (0)

__device__ __forceinline__ int swzQ(int Q) {
    return Q ^ ((Q >> 3) & 7) ^ ((Q >> 6) & 7);
}
__device__ __forceinline__ int uslot(int e) {
    return 2 * swzQ(e >> 1) + (e & 1);
}
__device__ __forceinline__ constexpr int inner_idx(int m, int jj) {
    return ((m >> (jj + 1)) << jj) + (m & ((1 << jj) - 1));
}

__device__ __forceinline__ void rot2(v2f& xl, v2f& xr, float c, float s) {
    v2f nl = c * xl + s * xr;
    v2f nr = c * xr - s * xl;
    xl = nl; xr = nr;
}

// f16-packed transposed table (identical to R10)
__global__ void __launch_bounds__(256) cs_kernel(const float* __restrict__ angles,
                                                 u32* __restrict__ TH, int n) {
    int i = blockIdx.x * blockDim.x + threadIdx.x;
    if (i >= n) return;
    float a = angles[i];
    float c = cosf(a), s = sinf(a);
    int l = i >> 11, aa = i & 2047;
    int region, jj, t, ii;
    if (l < 3)      { region = 0; jj = l;     t = aa >> 2;  ii = aa & 3; }
    else if (l < 6) { region = 1; jj = l - 3; int B = aa >> 5, r = aa & 31;
                      ii = r >> 3; t = 8 * B + (r & 7); }
    else if (l < 9) { region = 2; jj = l - 6; int S = aa >> 8, r = aa & 255;
                      ii = r >> 6; t = 64 * S + (r & 63); }
    else            { region = 3; jj = l - 9; ii = aa >> 9; t = aa & 511; }
    int a_idx = jj * 4 + ii;
    int flat = ((region * 3 + (a_idx >> 2)) * 512 + t) * 4 + (a_idx & 3);
    u32 lo = (u32)__half_as_ushort(__float2half(1.0f - c));
    u32 hi = (u32)__half_as_ushort(__float2half(s));
    TH[flat] = lo | (hi << 16);
}

#define UNPACK12(Ua, Ub, Uc, ca, sa) do {                                  \
    const u32 _u[12] = {Ua.x, Ua.y, Ua.z, Ua.w, Ub.x, Ub.y, Ub.z, Ub.w,    \
                        Uc.x, Uc.y, Uc.z, Uc.w};                           \
    _Pragma("unroll")                                                      \
    for (int a = 0; a < 12; ++a) {                                         \
        __half2 h2 = *reinterpret_cast<const __half2*>(&_u[a]);            \
        float2 f = __half22float2(h2);                                     \
        ca[a] = 1.0f - f.x;                                                \
        sa[a] = f.y;                                                       \
    }                                                                      \
} while (0)

#define PHASE_ROTS(ca, sa, w)                                              \
    _Pragma("unroll")                                                      \
    for (int jj = 0; jj < 3; ++jj) {                                       \
        const int st = 1 << jj;                                            \
        _Pragma("unroll")                                                  \
        for (int m = 0; m < 8; ++m) {                                      \
            if (!(m & st)) {                                               \
                const int a = jj * 4 + inner_idx(m, jj);                   \
                rot2(w[m], w[m + st], ca[a], sa[a]);                       \
            }                                                              \
        }                                                                  \
    }

// keep angle values (and their producing loads/unpack) live without rot
#define KEEP12(ca, sa) do {                                                \
    _Pragma("unroll")                                                      \
    for (int a = 0; a < 12; ++a) {                                         \
        asm volatile("" :: "v"(ca[a]), "v"(sa[a]));                        \
    }                                                                      \
} while (0)

#define CONST12(ca, sa) do {                                               \
    _Pragma("unroll")                                                      \
    for (int a = 0; a < 12; ++a) {                                         \
        ca[a] = 0.9990f;                                                   \
        sa[a] = 0.03125f + (float)a * 0.0009765625f;                       \
    }                                                                      \
} while (0)

template<int MODE>
__global__ void __launch_bounds__(BLOCK, 6)
butterfly_ab(const float* __restrict__ x, const uint4* __restrict__ TH4,
             float* __restrict__ out) {
    constexpr bool DO_ROT = (MODE != 1);
    constexpr bool DO_ANG = (MODE != 2);
    constexpr bool DO_LDS = (MODE != 3);
    __shared__ v2f buf[DIM];
    const int t = threadIdx.x;
    const long row0 = (long)blockIdx.x * 2;

    float ca[12], sa[12];

    #pragma unroll 1
    for (int rep = 0; rep < REP; ++rep) {
        v2f w[8];
        uint4 U0, U1, U2;
        if (DO_ANG) { U0 = TH4[t]; U1 = TH4[512 + t]; U2 = TH4[1024 + t]; }

        // ===== P1: e = 8t+k, layers 0-2; x direct from global =====
        {
            const float* p0 = x + row0 * DIM + 8 * t;
            const float* p1 = p0 + DIM;
            float4 a = *(const float4*)(p0),  b = *(const float4*)(p0 + 4);
            float4 c = *(const float4*)(p1),  d = *(const float4*)(p1 + 4);
            uint4 V0, V1, V2;
            if (DO_ANG) { V0 = TH4[3*512 + t]; V1 = TH4[4*512 + t]; V2 = TH4[5*512 + t]; }
            w[0] = v2f{a.x, c.x}; w[1] = v2f{a.y, c.y};
            w[2] = v2f{a.z, c.z}; w[3] = v2f{a.w, c.w};
            w[4] = v2f{b.x, d.x}; w[5] = v2f{b.y, d.y};
            w[6] = v2f{b.z, d.z}; w[7] = v2f{b.w, d.w};
            if (DO_ANG) UNPACK12(U0, U1, U2, ca, sa); else CONST12(ca, sa);
            if (DO_ROT) { PHASE_ROTS(ca, sa, w) } else { KEEP12(ca, sa); }
            if (DO_LDS) {
                #pragma unroll
                for (int wq = 0; wq < 4; ++wq) {
                    *(float4*)(&buf[2 * swzQ(4 * t + wq)]) =
                        make_float4(w[2*wq].x, w[2*wq].y, w[2*wq+1].x, w[2*wq+1].y);
                }
            }
            if (DO_ANG) { U0 = V0; U1 = V1; U2 = V2; }
        }
        if (DO_LDS) BAR();

        // ===== P2: e = 64(t>>3) + 8m + (t&7), layers 3-5 =====
        {
            uint4 V0, V1, V2;
            if (DO_ANG) { V0 = TH4[6*512 + t]; V1 = TH4[7*512 + t]; V2 = TH4[8*512 + t]; }
            int ps[8];
            if (DO_LDS) {
                const int eb = 64 * (t >> 3) + (t & 7);
                #pragma unroll
                for (int m = 0; m < 8; ++m) {
                    ps[m] = uslot(eb + 8 * m);
                    w[m] = buf[ps[m]];
                }
            }
            if (DO_ANG) UNPACK12(U0, U1, U2, ca, sa); else CONST12(ca, sa);
            if (DO_ROT) { PHASE_ROTS(ca, sa, w) } else { KEEP12(ca, sa); }
            if (DO_LDS) {
                #pragma unroll
                for (int m = 0; m < 8; ++m) buf[ps[m]] = w[m];
            }
            if (DO_ANG) { U0 = V0; U1 = V1; U2 = V2; }
        }
        if (DO_LDS) BAR();

        // ===== P3: e = 512(t>>6) + 64m + (t&63), layers 6-8 =====
        {
            uint4 V0, V1, V2;
            if (DO_ANG) { V0 = TH4[9*512 + t]; V1 = TH4[10*512 + t]; V2 = TH4[11*512 + t]; }
            int ps[8];
            if (DO_LDS) {
                const int eb = 512 * (t >> 6) + (t & 63);
                #pragma unroll
                for (int m = 0; m < 8; ++m) {
                    ps[m] = uslot(eb + 64 * m);
                    w[m] = buf[ps[m]];
                }
            }
            if (DO_ANG) UNPACK12(U0, U1, U2, ca, sa); else CONST12(ca, sa);
            if (DO_ROT) { PHASE_ROTS(ca, sa, w) } else { KEEP12(ca, sa); }
            if (DO_LDS) {
                #pragma unroll
                for (int m = 0; m < 8; ++m) buf[ps[m]] = w[m];
            }
            if (DO_ANG) { U0 = V0; U1 = V1; U2 = V2; }
        }
        if (DO_LDS) BAR();

        // ===== P4: e = t + 512m, layers 9-11; store =====
        {
            if (DO_LDS) {
                #pragma unroll
                for (int m = 0; m < 8; ++m) w[m] = buf[uslot(t + 512 * m)];
            }
            if (DO_ANG) UNPACK12(U0, U1, U2, ca, sa); else CONST12(ca, sa);
            if (DO_ROT) { PHASE_ROTS(ca, sa, w) } else { KEEP12(ca, sa); }
            float* o0 = out + row0 * DIM + t;
            float* o1 = o0 + DIM;
            #pragma unroll
            for (int m = 0; m < 8; ++m) {
                o0[m << 9] = w[m].x;
                o1[m << 9] = w[m].y;
            }
        }
        if (DO_LDS) BAR();   // next rep's P1 writes vs this P4's reads
    }
}

extern "C" void kernel_launch(void* const* d_in, const int* in_sizes, int n_in,
                              void* d_out, int out_size, void* d_ws, size_t ws_size,
                              hipStream_t stream) {
    (void)in_sizes; (void)n_in; (void)out_size; (void)ws_size;
    const float* x      = (const float*)d_in[0];
    const float* angles = (const float*)d_in[1];
    float* out = (float*)d_out;

    const int n = LAYERS * NANG;                    // 96 KiB table
    cs_kernel<<<(n + 255) / 256, 256, 0, stream>>>(angles, (u32*)d_ws, n);
    const uint4* T = (const uint4*)d_ws;
    const int grid = BATCH / 2;
    butterfly_ab<1><<<grid, BLOCK, 0, stream>>>(x, T, out);   // noROT
    butterfly_ab<2><<<grid, BLOCK, 0, stream>>>(x, T, out);   // noANG
    butterfly_ab<3><<<grid, BLOCK, 0, stream>>>(x, T, out);   // noLDS
    butterfly_ab<0><<<grid, BLOCK, 0, stream>>>(x, T, out);   // FULL (correct, last)
}

// Round 14
// 211.344 us; speedup vs baseline: 5.3091x; 5.3091x over previous
//
#include <hip/hip_runtime.h>
#include <hip/hip_fp16.h>

// ButterflyRotation R14: ABLATION, FIXED ATTRIBUTION. R10 body exactly;
// five DISTINCTLY-NAMED kernels, REP=1, full grid each, full runs LAST:
//   bfly_noROT: rot chains removed (angles kept live)    -> VALU-rot share
//   bfly_noANG: angle loads+unpack removed (consts)      -> angle share
//   bfly_noLDS: LDS round-trips + barriers removed       -> LDS share
//   bfly_noMEM: x loads + stores removed                 -> memory share
//   bfly_full : R10-exact (correct output)               -> baseline
// Read per-NAME dur_us from rocprof rows; bench total is a 5-pass sum.

#define DIM    4096
#define LAYERS 12
#define BATCH  8192
#define NANG   2048
#define BLOCK  512

typedef unsigned int u32;
typedef float v2f __attribute__((ext_vector_type(2)));

#define BAR() do {                                             \
    asm volatile("s_waitcnt lgkmcnt(0)" ::: "memory");         \
    __builtin_amdgcn_sched_barrier(0);                         \
    __builtin_amdgcn_s_barrier();                              \
} while (0)

__device__ __forceinline__ int swzQ(int Q) {
    return Q ^ ((Q >> 3) & 7) ^ ((Q >> 6) & 7);
}
__device__ __forceinline__ int uslot(int e) {
    return 2 * swzQ(e >> 1) + (e & 1);
}
__device__ __forceinline__ constexpr int inner_idx(int m, int jj) {
    return ((m >> (jj + 1)) << jj) + (m & ((1 << jj) - 1));
}

__device__ __forceinline__ void rot2(v2f& xl, v2f& xr, float c, float s) {
    v2f nl = c * xl + s * xr;
    v2f nr = c * xr - s * xl;
    xl = nl; xr = nr;
}

// f16-packed transposed table (identical to R10)
__global__ void __launch_bounds__(256) cs_kernel(const float* __restrict__ angles,
                                                 u32* __restrict__ TH, int n) {
    int i = blockIdx.x * blockDim.x + threadIdx.x;
    if (i >= n) return;
    float a = angles[i];
    float c = cosf(a), s = sinf(a);
    int l = i >> 11, aa = i & 2047;
    int region, jj, t, ii;
    if (l < 3)      { region = 0; jj = l;     t = aa >> 2;  ii = aa & 3; }
    else if (l < 6) { region = 1; jj = l - 3; int B = aa >> 5, r = aa & 31;
                      ii = r >> 3; t = 8 * B + (r & 7); }
    else if (l < 9) { region = 2; jj = l - 6; int S = aa >> 8, r = aa & 255;
                      ii = r >> 6; t = 64 * S + (r & 63); }
    else            { region = 3; jj = l - 9; ii = aa >> 9; t = aa & 511; }
    int a_idx = jj * 4 + ii;
    int flat = ((region * 3 + (a_idx >> 2)) * 512 + t) * 4 + (a_idx & 3);
    u32 lo = (u32)__half_as_ushort(__float2half(1.0f - c));
    u32 hi = (u32)__half_as_ushort(__float2half(s));
    TH[flat] = lo | (hi << 16);
}

#define UNPACK12(Ua, Ub, Uc, ca, sa) do {                                  \
    const u32 _u[12] = {Ua.x, Ua.y, Ua.z, Ua.w, Ub.x, Ub.y, Ub.z, Ub.w,    \
                        Uc.x, Uc.y, Uc.z, Uc.w};                           \
    _Pragma("unroll")                                                      \
    for (int a = 0; a < 12; ++a) {                                         \
        __half2 h2 = *reinterpret_cast<const __half2*>(&_u[a]);            \
        float2 f = __half22float2(h2);                                     \
        ca[a] = 1.0f - f.x;                                                \
        sa[a] = f.y;                                                       \
    }                                                                      \
} while (0)

#define PHASE_ROTS(ca, sa, w)                                              \
    _Pragma("unroll")                                                      \
    for (int jj = 0; jj < 3; ++jj) {                                       \
        const int st = 1 << jj;                                            \
        _Pragma("unroll")                                                  \
        for (int m = 0; m < 8; ++m) {                                      \
            if (!(m & st)) {                                               \
                const int a = jj * 4 + inner_idx(m, jj);                   \
                rot2(w[m], w[m + st], ca[a], sa[a]);                       \
            }                                                              \
        }                                                                  \
    }

#define KEEP12(ca, sa) do {                                                \
    _Pragma("unroll")                                                      \
    for (int a = 0; a < 12; ++a) {                                         \
        asm volatile("" :: "v"(ca[a]), "v"(sa[a]));                        \
    }                                                                      \
} while (0)

#define CONST12(ca, sa) do {                                               \
    _Pragma("unroll")                                                      \
    for (int a = 0; a < 12; ++a) {                                         \
        ca[a] = 0.9990f;                                                   \
        sa[a] = 0.03125f + (float)a * 0.0009765625f;                       \
    }                                                                      \
} while (0)

// MODE: 0 full, 1 noROT, 2 noANG, 3 noLDS, 4 noMEM
template<int MODE>
__device__ __forceinline__ void bfly_body(const float* __restrict__ x,
                                          const uint4* __restrict__ TH4,
                                          float* __restrict__ out) {
    constexpr bool DO_ROT = (MODE != 1);
    constexpr bool DO_ANG = (MODE != 2);
    constexpr bool DO_LDS = (MODE != 3);
    constexpr bool DO_MEM = (MODE != 4);
    __shared__ v2f buf[DIM];
    const int t = threadIdx.x;
    const long row0 = (long)blockIdx.x * 2;

    float ca[12], sa[12];
    v2f w[8];
    uint4 U0, U1, U2;
    if (DO_ANG) { U0 = TH4[t]; U1 = TH4[512 + t]; U2 = TH4[1024 + t]; }

    // ===== P1: e = 8t+k, layers 0-2 =====
    {
        if (DO_MEM) {
            const float* p0 = x + row0 * DIM + 8 * t;
            const float* p1 = p0 + DIM;
            float4 a = *(const float4*)(p0),  b = *(const float4*)(p0 + 4);
            float4 c = *(const float4*)(p1),  d = *(const float4*)(p1 + 4);
            w[0] = v2f{a.x, c.x}; w[1] = v2f{a.y, c.y};
            w[2] = v2f{a.z, c.z}; w[3] = v2f{a.w, c.w};
            w[4] = v2f{b.x, d.x}; w[5] = v2f{b.y, d.y};
            w[6] = v2f{b.z, d.z}; w[7] = v2f{b.w, d.w};
        } else {
            #pragma unroll
            for (int m = 0; m < 8; ++m)
                w[m] = v2f{(float)(t + m), (float)(t - m)};
        }
        uint4 V0, V1, V2;
        if (DO_ANG) { V0 = TH4[3*512 + t]; V1 = TH4[4*512 + t]; V2 = TH4[5*512 + t]; }
        if (DO_ANG) UNPACK12(U0, U1, U2, ca, sa); else CONST12(ca, sa);
        if (DO_ROT) { PHASE_ROTS(ca, sa, w) } else { KEEP12(ca, sa); }
        if (DO_LDS) {
            #pragma unroll
            for (int wq = 0; wq < 4; ++wq) {
                *(float4*)(&buf[2 * swzQ(4 * t + wq)]) =
                    make_float4(w[2*wq].x, w[2*wq].y, w[2*wq+1].x, w[2*wq+1].y);
            }
        }
        if (DO_ANG) { U0 = V0; U1 = V1; U2 = V2; }
    }
    if (DO_LDS) BAR();

    // ===== P2: e = 64(t>>3) + 8m + (t&7), layers 3-5 =====
    {
        uint4 V0, V1, V2;
        if (DO_ANG) { V0 = TH4[6*512 + t]; V1 = TH4[7*512 + t]; V2 = TH4[8*512 + t]; }
        int ps[8];
        if (DO_LDS) {
            const int eb = 64 * (t >> 3) + (t & 7);
            #pragma unroll
            for (int m = 0; m < 8; ++m) {
                ps[m] = uslot(eb + 8 * m);
                w[m] = buf[ps[m]];
            }
        }
        if (DO_ANG) UNPACK12(U0, U1, U2, ca, sa); else CONST12(ca, sa);
        if (DO_ROT) { PHASE_ROTS(ca, sa, w) } else { KEEP12(ca, sa); }
        if (DO_LDS) {
            #pragma unroll
            for (int m = 0; m < 8; ++m) buf[ps[m]] = w[m];
        }
        if (DO_ANG) { U0 = V0; U1 = V1; U2 = V2; }
    }
    if (DO_LDS) BAR();

    // ===== P3: e = 512(t>>6) + 64m + (t&63), layers 6-8 =====
    {
        uint4 V0, V1, V2;
        if (DO_ANG) { V0 = TH4[9*512 + t]; V1 = TH4[10*512 + t]; V2 = TH4[11*512 + t]; }
        int ps[8];
        if (DO_LDS) {
            const int eb = 512 * (t >> 6) + (t & 63);
            #pragma unroll
            for (int m = 0; m < 8; ++m) {
                ps[m] = uslot(eb + 64 * m);
                w[m] = buf[ps[m]];
            }
        }
        if (DO_ANG) UNPACK12(U0, U1, U2, ca, sa); else CONST12(ca, sa);
        if (DO_ROT) { PHASE_ROTS(ca, sa, w) } else { KEEP12(ca, sa); }
        if (DO_LDS) {
            #pragma unroll
            for (int m = 0; m < 8; ++m) buf[ps[m]] = w[m];
        }
        if (DO_ANG) { U0 = V0; U1 = V1; U2 = V2; }
    }
    if (DO_LDS) BAR();

    // ===== P4: e = t + 512m, layers 9-11; store =====
    {
        if (DO_LDS) {
            #pragma unroll
            for (int m = 0; m < 8; ++m) w[m] = buf[uslot(t + 512 * m)];
        }
        if (DO_ANG) UNPACK12(U0, U1, U2, ca, sa); else CONST12(ca, sa);
        if (DO_ROT) { PHASE_ROTS(ca, sa, w) } else { KEEP12(ca, sa); }
        if (DO_MEM) {
            float* o0 = out + row0 * DIM + t;
            float* o1 = o0 + DIM;
            #pragma unroll
            for (int m = 0; m < 8; ++m) {
                o0[m << 9] = w[m].x;
                o1[m << 9] = w[m].y;
            }
        } else {
            #pragma unroll
            for (int m = 0; m < 8; ++m)
                asm volatile("" :: "v"(w[m].x), "v"(w[m].y));
        }
    }
}

__global__ void __launch_bounds__(BLOCK, 6)
bfly_noROT(const float* __restrict__ x, const uint4* __restrict__ T,
           float* __restrict__ out) { bfly_body<1>(x, T, out); }
__global__ void __launch_bounds__(BLOCK, 6)
bfly_noANG(const float* __restrict__ x, const uint4* __restrict__ T,
           float* __restrict__ out) { bfly_body<2>(x, T, out); }
__global__ void __launch_bounds__(BLOCK, 6)
bfly_noLDS(const float* __restrict__ x, const uint4* __restrict__ T,
           float* __restrict__ out) { bfly_body<3>(x, T, out); }
__global__ void __launch_bounds__(BLOCK, 6)
bfly_noMEM(const float* __restrict__ x, const uint4* __restrict__ T,
           float* __restrict__ out) { bfly_body<4>(x, T, out); }
__global__ void __launch_bounds__(BLOCK, 6)
bfly_full(const float* __restrict__ x, const uint4* __restrict__ T,
          float* __restrict__ out) { bfly_body<0>(x, T, out); }

extern "C" void kernel_launch(void* const* d_in, const int* in_sizes, int n_in,
                              void* d_out, int out_size, void* d_ws, size_t ws_size,
                              hipStream_t stream) {
    (void)in_sizes; (void)n_in; (void)out_size; (void)ws_size;
    const float* x      = (const float*)d_in[0];
    const float* angles = (const float*)d_in[1];
    float* out = (float*)d_out;

    const int n = LAYERS * NANG;                    // 96 KiB table
    cs_kernel<<<(n + 255) / 256, 256, 0, stream>>>(angles, (u32*)d_ws, n);
    const uint4* T = (const uint4*)d_ws;
    const int grid = BATCH / 2;
    bfly_noROT<<<grid, BLOCK, 0, stream>>>(x, T, out);
    bfly_noANG<<<grid, BLOCK, 0, stream>>>(x, T, out);
    bfly_noLDS<<<grid, BLOCK, 0, stream>>>(x, T, out);
    bfly_noMEM<<<grid, BLOCK, 0, stream>>>(x, T, out);
    bfly_full<<<grid, BLOCK, 0, stream>>>(x, T, out);   // correct output, LAST
}

// Round 15
// 53.403 us; speedup vs baseline: 21.0109x; 3.9575x over previous
//
#include <hip/hip_runtime.h>
#include <hip/hip_fp16.h>

// ButterflyRotation: 12 butterfly layers over rows of 4096 fp32.
// R15: R10 EXACTLY (best: 53.2 us) + non-temporal output stores.
// out is write-once/never-re-read: nt (evict-first) keeps its 134 MB out
// of Infinity Cache, so x (134 MB) stays L3-resident across graph replays
// -> steady-state FETCH drops, HBM traffic ~= writes only.
// Structure: BLOCK=512, 2 rows packed v2f in interleaved 32 KiB LDS,
// radix-8 x 4 phases, f16 {1-cos,sin} transposed table (96 KiB),
// one-phase-ahead angle prefetch, 3 lgkm-only barriers, grid 4096.
//   P1: e = 8t+m                    -> layers 0-2   (x direct from global)
//   P2: e = 64(t>>3)+8m+(t&7)       -> layers 3-5
//   P3: e = 512(t>>6)+64m+(t&63)    -> layers 6-8
//   P4: e = t+512m                  -> layers 9-11  (nt coalesced store)

#define DIM    4096
#define LAYERS 12
#define BATCH  8192
#define NANG   2048
#define BLOCK  512

typedef unsigned int u32;
typedef float v2f __attribute__((ext_vector_type(2)));

// lgkm-only barrier: global loads stay in flight across it
#define BAR() do {                                             \
    asm volatile("s_waitcnt lgkmcnt(0)" ::: "memory");         \
    __builtin_amdgcn_sched_barrier(0);                         \
    __builtin_amdgcn_s_barrier();                              \
} while (0)

// quad-level swizzle (involution: only bits 0-2 change)
__device__ __forceinline__ int swzQ(int Q) {
    return Q ^ ((Q >> 3) & 7) ^ ((Q >> 6) & 7);
}
// element -> interleaved 8B-unit slot (quad swizzle in packed space)
__device__ __forceinline__ int uslot(int e) {
    return 2 * swzQ(e >> 1) + (e & 1);
}
// butterfly sub-index for left element m at local level jj (stride 2^jj)
__device__ __forceinline__ constexpr int inner_idx(int m, int jj) {
    return ((m >> (jj + 1)) << jj) + (m & ((1 << jj) - 1));
}

// packed rotation on both rows at once
__device__ __forceinline__ void rot2(v2f& xl, v2f& xr, float c, float s) {
    v2f nl = c * xl + s * xr;
    v2f nr = c * xr - s * xl;
    xl = nl; xr = nr;
}

// f16-packed transposed table: 12 groups x 512 threads x uint4
// (u32 component a&3 of group (region*3 + (a>>2)) holds angle a = jj*4+ii
//  of that phase for thread t, packed {h(1-c) | h(s)<<16}). 96 KiB.
__global__ void __launch_bounds__(256) cs_kernel(const float* __restrict__ angles,
                                                 u32* __restrict__ TH, int n) {
    int i = blockIdx.x * blockDim.x + threadIdx.x;
    if (i >= n) return;
    float a = angles[i];
    float c = cosf(a), s = sinf(a);
    int l = i >> 11, aa = i & 2047;
    int region, jj, t, ii;
    if (l < 3)      { region = 0; jj = l;     t = aa >> 2;  ii = aa & 3; }
    else if (l < 6) { region = 1; jj = l - 3; int B = aa >> 5, r = aa & 31;
                      ii = r >> 3; t = 8 * B + (r & 7); }
    else if (l < 9) { region = 2; jj = l - 6; int S = aa >> 8, r = aa & 255;
                      ii = r >> 6; t = 64 * S + (r & 63); }
    else            { region = 3; jj = l - 9; ii = aa >> 9; t = aa & 511; }
    int a_idx = jj * 4 + ii;
    int flat = ((region * 3 + (a_idx >> 2)) * 512 + t) * 4 + (a_idx & 3);
    u32 lo = (u32)__half_as_ushort(__float2half(1.0f - c));
    u32 hi = (u32)__half_as_ushort(__float2half(s));
    TH[flat] = lo | (hi << 16);
}

// unpack 3 uint4 -> 12 (c,s) pairs (compile-time indices after unroll)
#define UNPACK12(Ua, Ub, Uc, ca, sa) do {                                  \
    const u32 _u[12] = {Ua.x, Ua.y, Ua.z, Ua.w, Ub.x, Ub.y, Ub.z, Ub.w,    \
                        Uc.x, Uc.y, Uc.z, Uc.w};                           \
    _Pragma("unroll")                                                      \
    for (int a = 0; a < 12; ++a) {                                         \
        __half2 h2 = *reinterpret_cast<const __half2*>(&_u[a]);            \
        float2 f = __half22float2(h2);                                     \
        ca[a] = 1.0f - f.x;                                                \
        sa[a] = f.y;                                                       \
    }                                                                      \
} while (0)

// one phase = 3 layers (local strides 1,2,4) on packed w[8]
#define PHASE_ROTS(ca, sa, w)                                              \
    _Pragma("unroll")                                                      \
    for (int jj = 0; jj < 3; ++jj) {                                       \
        const int st = 1 << jj;                                            \
        _Pragma("unroll")                                                  \
        for (int m = 0; m < 8; ++m) {                                      \
            if (!(m & st)) {                                               \
                const int a = jj * 4 + inner_idx(m, jj);                   \
                rot2(w[m], w[m + st], ca[a], sa[a]);                       \
            }                                                              \
        }                                                                  \
    }

__global__ void __launch_bounds__(BLOCK, 6)
butterfly_kernel(const float* __restrict__ x, const uint4* __restrict__ TH4,
                 float* __restrict__ out) {
    __shared__ v2f buf[DIM];                // 32 KiB interleaved {r0[e], r1[e]}
    const int t = threadIdx.x;
    const long row0 = (long)blockIdx.x * 2;

    v2f w[8];
    float ca[12], sa[12];

    // ===== P1: e = 8t+k, layers 0-2; x direct from global =====
    {
        // current-phase angles + x data
        uint4 A0 = TH4[0 * 512 + t], A1 = TH4[1 * 512 + t], A2 = TH4[2 * 512 + t];
        const float* p0 = x + row0 * DIM + 8 * t;
        const float* p1 = p0 + DIM;
        float4 a = *(const float4*)(p0),     b = *(const float4*)(p0 + 4);
        float4 c = *(const float4*)(p1),     d = *(const float4*)(p1 + 4);
        // prefetch P2 angles (fly across BAR)
        uint4 B0 = TH4[3 * 512 + t], B1 = TH4[4 * 512 + t], B2 = TH4[5 * 512 + t];

        w[0] = v2f{a.x, c.x}; w[1] = v2f{a.y, c.y};
        w[2] = v2f{a.z, c.z}; w[3] = v2f{a.w, c.w};
        w[4] = v2f{b.x, d.x}; w[5] = v2f{b.y, d.y};
        w[6] = v2f{b.z, d.z}; w[7] = v2f{b.w, d.w};
        UNPACK12(A0, A1, A2, ca, sa);
        PHASE_ROTS(ca, sa, w)
        // b128 writes: units (2Q', 2Q'+1), Q' = swzQ(4t+q)
        #pragma unroll
        for (int q = 0; q < 4; ++q) {
            *(float4*)(&buf[2 * swzQ(4 * t + q)]) =
                make_float4(w[2*q].x, w[2*q].y, w[2*q+1].x, w[2*q+1].y);
        }
        BAR();

        // ===== P2: e = 64(t>>3) + 8m + (t&7), layers 3-5 (b64) =====
        // prefetch P3 angles first (no wait), then consume B*
        uint4 C0 = TH4[6 * 512 + t], C1 = TH4[7 * 512 + t], C2 = TH4[8 * 512 + t];
        {
            const int eb = 64 * (t >> 3) + (t & 7);
            int ps[8];
            #pragma unroll
            for (int m = 0; m < 8; ++m) {
                ps[m] = uslot(eb + 8 * m);
                w[m] = buf[ps[m]];
            }
            UNPACK12(B0, B1, B2, ca, sa);
            PHASE_ROTS(ca, sa, w)
            #pragma unroll
            for (int m = 0; m < 8; ++m) buf[ps[m]] = w[m];   // own slots
        }
        BAR();

        // ===== P3: e = 512(t>>6) + 64m + (t&63), layers 6-8 (b64) =====
        // prefetch P4 angles first, then consume C*
        uint4 D0 = TH4[9 * 512 + t], D1 = TH4[10 * 512 + t], D2 = TH4[11 * 512 + t];
        {
            const int eb = 512 * (t >> 6) + (t & 63);
            int ps[8];
            #pragma unroll
            for (int m = 0; m < 8; ++m) {
                ps[m] = uslot(eb + 64 * m);
                w[m] = buf[ps[m]];
            }
            UNPACK12(C0, C1, C2, ca, sa);
            PHASE_ROTS(ca, sa, w)
            #pragma unroll
            for (int m = 0; m < 8; ++m) buf[ps[m]] = w[m];
        }
        BAR();

        // ===== P4: e = t + 512m, layers 9-11 (b64); NT store =====
        {
            #pragma unroll
            for (int m = 0; m < 8; ++m) w[m] = buf[uslot(t + 512 * m)];
            UNPACK12(D0, D1, D2, ca, sa);
            PHASE_ROTS(ca, sa, w)
            float* o0 = out + row0 * DIM + t;
            float* o1 = o0 + DIM;
            #pragma unroll
            for (int m = 0; m < 8; ++m) {
                __builtin_nontemporal_store(w[m].x, o0 + (m << 9));
                __builtin_nontemporal_store(w[m].y, o1 + (m << 9));
            }
        }
    }
}

extern "C" void kernel_launch(void* const* d_in, const int* in_sizes, int n_in,
                              void* d_out, int out_size, void* d_ws, size_t ws_size,
                              hipStream_t stream) {
    (void)in_sizes; (void)n_in; (void)out_size; (void)ws_size;
    const float* x      = (const float*)d_in[0];
    const float* angles = (const float*)d_in[1];
    float* out = (float*)d_out;

    const int n = LAYERS * NANG;                    // 24576 angles, 96 KiB table
    cs_kernel<<<(n + 255) / 256, 256, 0, stream>>>(angles, (u32*)d_ws, n);
    butterfly_kernel<<<BATCH / 2, BLOCK, 0, stream>>>(x, (const uint4*)d_ws, out);
}